// Round 1
// baseline (49.078 us; speedup 1.0000x reference)
//
#include <hip/hip_runtime.h>
#include <math.h>

// LightingProbes: N points, 5x5x5 probe grid on [-3,3] (h=1.5), K=4 nearest,
// cubemaps (125,6,16,16,3) f32. One thread per point.
//
// Selection: top-4 nearest probes restricted to the 27-candidate set formed by
// the 3 nearest grid coords per dimension (provably contains the true top-4).
// Keys are dist=sqrt(max(d2,0)) with strict-< insertion in ascending probe
// index order -> matches jax.lax.top_k tie-break (lower index first).

#define GRID_LO  -3.0f
#define GRID_H    1.5f

__device__ __forceinline__ int dim_start(float v) {
    // nearest grid index n = round((v+3)/1.5), candidates {s, s+1, s+2}, s = clamp(n-1, 0, 2)
    float f = (v + 3.0f) * (1.0f / 1.5f);
    int n = (int)floorf(f + 0.5f);
    n = n < 0 ? 0 : (n > 4 ? 4 : n);
    int s = n - 1;
    s = s < 0 ? 0 : (s > 2 ? 2 : s);
    return s;
}

__global__ __launch_bounds__(256) void lighting_probes_kernel(
    const float* __restrict__ xyz,
    const float* __restrict__ vdirs,
    const float* __restrict__ cube,
    float* __restrict__ out,
    int N)
{
    int i = blockIdx.x * blockDim.x + threadIdx.x;
    if (i >= N) return;

    float x = __builtin_nontemporal_load(&xyz[3 * i + 0]);
    float y = __builtin_nontemporal_load(&xyz[3 * i + 1]);
    float z = __builtin_nontemporal_load(&xyz[3 * i + 2]);

    float dx = __builtin_nontemporal_load(&vdirs[3 * i + 0]);
    float dy = __builtin_nontemporal_load(&vdirs[3 * i + 1]);
    float dz = __builtin_nontemporal_load(&vdirs[3 * i + 2]);

    // ---- top-4 probe selection over 27 grid candidates ----
    float x2 = fmaf(x, x, fmaf(y, y, z * z));
    int sx = dim_start(x), sy = dim_start(y), sz = dim_start(z);

    float d0v = 1e30f, d1v = 1e30f, d2v = 1e30f, d3v = 1e30f;
    int   i0 = 0, i1 = 0, i2 = 0, i3 = 0;

#pragma unroll
    for (int a = 0; a < 3; a++) {
        const int ixg = sx + a;
        const float px = GRID_LO + GRID_H * (float)ixg;
#pragma unroll
        for (int b = 0; b < 3; b++) {
            const int iyg = sy + b;
            const float py = GRID_LO + GRID_H * (float)iyg;
#pragma unroll
            for (int c = 0; c < 3; c++) {
                const int izg = sz + c;
                const float pz = GRID_LO + GRID_H * (float)izg;

                float dot = fmaf(x, px, fmaf(y, py, z * pz));
                float p2  = fmaf(px, px, fmaf(py, py, pz * pz));
                float dd  = fmaf(-2.0f, dot, x2 + p2);
                dd = fmaxf(dd, 0.0f);
                float dist = sqrtf(dd);
                int idx = (ixg * 5 + iyg) * 5 + izg;

                // sorted insert (ascending dist), strict < keeps earlier (lower idx) on tie
                {
                    bool lt = dist < d3v;
                    d3v = lt ? dist : d3v; i3 = lt ? idx : i3;
                }
                {
                    bool cb = d3v < d2v;
                    float nd2 = cb ? d3v : d2v, nd3 = cb ? d2v : d3v;
                    int   ni2 = cb ? i3 : i2,   ni3 = cb ? i2 : i3;
                    d2v = nd2; d3v = nd3; i2 = ni2; i3 = ni3;
                }
                {
                    bool cb = d2v < d1v;
                    float nd1 = cb ? d2v : d1v, nd2 = cb ? d1v : d2v;
                    int   ni1 = cb ? i2 : i1,   ni2 = cb ? i1 : i2;
                    d1v = nd1; d2v = nd2; i1 = ni1; i2 = ni2;
                }
                {
                    bool cb = d1v < d0v;
                    float nd0 = cb ? d1v : d0v, nd1 = cb ? d0v : d1v;
                    int   ni0 = cb ? i1 : i0,   ni1 = cb ? i0 : i1;
                    d0v = nd0; d1v = nd1; i0 = ni0; i1 = ni1;
                }
            }
        }
    }

    // ---- weights ----
    float w0 = 1.0f / (d0v + 1e-4f);
    float w1 = 1.0f / (d1v + 1e-4f);
    float w2 = 1.0f / (d2v + 1e-4f);
    float w3 = 1.0f / (d3v + 1e-4f);
    float winv = 1.0f / (w0 + w1 + w2 + w3);
    w0 *= winv; w1 *= winv; w2 *= winv; w3 *= winv;

    // ---- direction -> face, uv ----
    float nrm = sqrtf(fmaf(dx, dx, fmaf(dy, dy, dz * dz)));
    nrm = fmaxf(nrm, 1e-12f);
    float inv = 1.0f / nrm;
    float ux = dx * inv, uy = dy * inv, uz = dz * inv;
    float ax = fabsf(ux), ay = fabsf(uy), az = fabsf(uz);

    bool xd = (ax >= ay) && (ax >= az);
    int face;
    float den, un, vn;
    if (xd) {
        face = (ux > 0.0f) ? 0 : 1;
        den = ax;
        un = (ux > 0.0f) ? -uz : uz;
        vn = -uy;
    } else if (ay >= az) {
        face = (uy > 0.0f) ? 2 : 3;
        den = ay;
        un = ux;
        vn = (uy > 0.0f) ? uz : -uz;
    } else {
        face = (uz > 0.0f) ? 4 : 5;
        den = az;
        un = (uz > 0.0f) ? ux : -ux;
        vn = -uy;
    }
    float rden = 1.0f / (den + 1e-8f);
    float u = un * rden;
    float v = vn * rden;
    u = fminf(1.0f, fmaxf(-1.0f, u));
    v = fminf(1.0f, fmaxf(-1.0f, v));

    // ---- bilinear coords (W=H=16) ----
    float fx = (u + 1.0f) * 0.5f * 15.0f;
    float fy = (v + 1.0f) * 0.5f * 15.0f;
    float x0f = floorf(fx), y0f = floorf(fy);
    float wx = fx - x0f, wy = fy - y0f;
    int px0 = (int)x0f; px0 = px0 < 0 ? 0 : (px0 > 15 ? 15 : px0);
    int py0 = (int)y0f; py0 = py0 < 0 ? 0 : (py0 > 15 ? 15 : py0);
    int px1 = px0 + 1 > 15 ? 15 : px0 + 1;
    int py1 = py0 + 1 > 15 ? 15 : py0 + 1;

    float w00 = (1.0f - wx) * (1.0f - wy);
    float w01 = wx * (1.0f - wy);
    float w10 = (1.0f - wx) * wy;
    float w11 = wx * wy;

    int faceoff = face * 768;              // 16*16*3
    int t00 = (py0 * 16 + px0) * 3;
    int t01 = (py0 * 16 + px1) * 3;
    int t10 = (py1 * 16 + px0) * 3;
    int t11 = (py1 * 16 + px1) * 3;

    float accr = 0.0f, accg = 0.0f, accb = 0.0f;
#pragma unroll
    for (int k = 0; k < 4; k++) {
        int   p  = (k == 0) ? i0 : (k == 1) ? i1 : (k == 2) ? i2 : i3;
        float wn = (k == 0) ? w0 : (k == 1) ? w1 : (k == 2) ? w2 : w3;
        int base = p * 4608 + faceoff;     // 6*16*16*3 per probe
        int o00 = base + t00, o01 = base + t01, o10 = base + t10, o11 = base + t11;
#pragma unroll
        for (int ch = 0; ch < 3; ch++) {
            float v00 = cube[o00 + ch];
            float v01 = cube[o01 + ch];
            float v10 = cube[o10 + ch];
            float v11 = cube[o11 + ch];
            float val = fmaf(v00, w00, fmaf(v01, w01, fmaf(v10, w10, v11 * w11)));
            if (ch == 0) accr = fmaf(wn, val, accr);
            else if (ch == 1) accg = fmaf(wn, val, accg);
            else accb = fmaf(wn, val, accb);
        }
    }

    __builtin_nontemporal_store(accr, &out[3 * i + 0]);
    __builtin_nontemporal_store(accg, &out[3 * i + 1]);
    __builtin_nontemporal_store(accb, &out[3 * i + 2]);
}

extern "C" void kernel_launch(void* const* d_in, const int* in_sizes, int n_in,
                              void* d_out, int out_size, void* d_ws, size_t ws_size,
                              hipStream_t stream) {
    const float* xyz  = (const float*)d_in[0];
    const float* vd   = (const float*)d_in[1];
    const float* cube = (const float*)d_in[2];
    float* outp = (float*)d_out;
    int N = in_sizes[0] / 3;
    int blocks = (N + 255) / 256;
    hipLaunchKernelGGL(lighting_probes_kernel, dim3(blocks), dim3(256), 0, stream,
                       xyz, vd, cube, outp, N);
}